// Round 10
// baseline (363.682 us; speedup 1.0000x reference)
//
#include <hip/hip_runtime.h>
#include <hip/hip_bf16.h>
#include <stdint.h>

// ---- All intermediates live inside d_out (16,777,216 f32; 256 slots x 65536 f32).
// Slot q (q=b*64+co): [0,4096) feat plane q ; [4096,8192) cat plane p (p<256, p&255==q)
// [8192,12288) cat plane p (p>=256) ; [12288] mean ; [12289] att ;
// [16384,24576) f64 x1_hi plane q (4096 doubles).
__device__ __forceinline__ float* catp(float* o, int p) {
    return o + (size_t)(p & 255) * 65536 + 4096 + ((p >> 8) << 12);
}
__device__ __forceinline__ double* x1hp(float* o, int q) {
    return (double*)(o + (size_t)q * 65536 + 16384);
}

// ---------------- K1: 4x4/stride-4 conv + BN + ReLU in f64 -> f32 cat ch 0..63 + f64 x1_hi
__global__ __launch_bounds__(256) void k1_convds(
    const float* __restrict__ x, const float* __restrict__ wd, const float* __restrict__ bd,
    const float* __restrict__ g, const float* __restrict__ be,
    const float* __restrict__ m, const float* __restrict__ v,
    float* __restrict__ o)
{
    __shared__ __align__(16) float tile[32 * 4 * 64];
    int blk = blockIdx.x;
    int jt = blk & 3, i = (blk >> 2) & 63, b = blk >> 8;
    int t = threadIdx.x;
    int co = t & 63, jg = t >> 6;
    double acc0 = 0.0, acc1 = 0.0, acc2 = 0.0, acc3 = 0.0;
    for (int half = 0; half < 2; ++half) {
        __syncthreads();
        for (int kk = 0; kk < 8; ++kk) {
            int ch = t + 256 * kk;
            int ci = ch >> 6, y4 = (ch >> 4) & 3, x4 = ch & 15;
            const float* src = x + (((b * 64 + half * 32 + ci) * 256 + (i * 4 + y4)) * 256 + jt * 64 + x4 * 4);
            *(float4*)(tile + (ci * 4 + y4) * 64 + x4 * 4) = *(const float4*)src;
        }
        __syncthreads();
        const float* wco = wd + co * 1024 + half * 512;
        for (int ci = 0; ci < 32; ++ci) {
            #pragma unroll
            for (int ky = 0; ky < 4; ++ky) {
                float4 wv4 = *(const float4*)(wco + ci * 16 + ky * 4);
                double w0 = (double)wv4.x, w1d = (double)wv4.y, w2d = (double)wv4.z, w3d = (double)wv4.w;
                const float* xr = tile + (ci * 4 + ky) * 64 + jg * 16;
                float4 a0 = *(const float4*)(xr);
                float4 a1 = *(const float4*)(xr + 4);
                float4 a2 = *(const float4*)(xr + 8);
                float4 a3 = *(const float4*)(xr + 12);
                acc0 = fma(w0, (double)a0.x, fma(w1d, (double)a0.y, fma(w2d, (double)a0.z, fma(w3d, (double)a0.w, acc0))));
                acc1 = fma(w0, (double)a1.x, fma(w1d, (double)a1.y, fma(w2d, (double)a1.z, fma(w3d, (double)a1.w, acc1))));
                acc2 = fma(w0, (double)a2.x, fma(w1d, (double)a2.y, fma(w2d, (double)a2.z, fma(w3d, (double)a2.w, acc2))));
                acc3 = fma(w0, (double)a3.x, fma(w1d, (double)a3.y, fma(w2d, (double)a3.z, fma(w3d, (double)a3.w, acc3))));
            }
        }
    }
    double sc = (double)g[co] / sqrt((double)v[co] + 1e-5);
    double sh = (double)bd[co] - (double)m[co];
    double bb = (double)be[co];
    double o0 = fmax(0.0, (acc0 + sh) * sc + bb);
    double o1 = fmax(0.0, (acc1 + sh) * sc + bb);
    double o2 = fmax(0.0, (acc2 + sh) * sc + bb);
    double o3 = fmax(0.0, (acc3 + sh) * sc + bb);
    int pos = i * 64 + jt * 16 + jg * 4;
    float4 ov;
    ov.x = (float)o0; ov.y = (float)o1; ov.z = (float)o2; ov.w = (float)o3;
    *(float4*)(catp(o, b * 128 + co) + pos) = ov;
    double* xh = x1hp(o, b * 64 + co);
    *(double2*)(xh + pos) = make_double2(o0, o1);
    *(double2*)(xh + pos + 2) = make_double2(o2, o3);
}

// ---------------- K2: windowed d^2 from f64 x1_hi -> top-9 largest d^2 -> f32 neighbor-mean diff
// grid: 256 = B*64 rows; block 256. LDS ~45.6KB (15232B tile aliased f64-phase1/f32-phase4).
__global__ __launch_bounds__(256) void k2_feat(float* __restrict__ o)
{
    __shared__ __align__(16) char smem[15232];          // phase1: double tile [(r*4+c)*66+col]; phase4: float [(r*8+c)*68+col]
    __shared__ double dotsd[64 * 50];                   // 25600B
    __shared__ double sqd[7 * 64];                      // 3584B
    __shared__ int sels[64 * 9];                        // 2304B
    double* tile_d = (double*)smem;
    float* tileq = (float*)smem;
    int blk = blockIdx.x;
    int b = blk >> 6, i = blk & 63;
    int t = threadIdx.x;
    int lane = t & 63, wv = t >> 6;

    for (int p = t; p < 64 * 50; p += 256) dotsd[p] = 0.0;
    for (int p = t; p < 448; p += 256) sqd[p] = 0.0;

    // phase 1: accumulate sq + window dots in f64 over 16 stages of 4 channels
    for (int q = 0; q < 16; ++q) {
        __syncthreads();
        for (int s = t; s < 896; s += 256) {            // 7r x 4ch x 32 double2 chunks
            int rc = s >> 5, c2 = s & 31;
            int r = rc >> 2, c = rc & 3;
            int gr = i - 3 + r;
            if (gr >= 0 && gr <= 63) {
                const double* src = x1hp(o, b * 64 + q * 4 + c);
                *(double2*)(tile_d + rc * 66 + c2 * 2) = *(const double2*)(src + gr * 64 + c2 * 2);
            }
        }
        __syncthreads();
        for (int p = t; p < 448; p += 256) {
            int r = p >> 6, col = p & 63;
            int gr = i - 3 + r;
            if (gr >= 0 && gr <= 63) {
                double s = 0.0;
                #pragma unroll
                for (int c = 0; c < 4; ++c) {
                    double xv = tile_d[(r * 4 + c) * 66 + col];
                    s = fma(xv, xv, s);
                }
                sqd[p] += s;
            }
        }
        double xlq[4];
        #pragma unroll
        for (int c = 0; c < 4; ++c) xlq[c] = tile_d[(12 + c) * 66 + lane];
        for (int oo = wv; oo < 49; oo += 4) {
            int oi = oo / 7 - 3, oj = oo % 7 - 3;
            int mi = i + oi, mj = lane + oj;
            if (mi >= 0 && mi <= 63 && mj >= 0 && mj <= 63) {
                int r = oi + 3;
                double dot = 0.0;
                #pragma unroll
                for (int c = 0; c < 4; ++c) dot = fma(xlq[c], tile_d[(r * 4 + c) * 66 + mj], dot);
                dotsd[lane * 50 + oo] += dot;
            }
        }
    }
    __syncthreads();
    // phase 2: to d^2 (invalid -> -1e300)
    for (int oo = wv; oo < 49; oo += 4) {
        int oi = oo / 7 - 3, oj = oo % 7 - 3;
        int mi = i + oi, mj = lane + oj;
        double d2 = -1e300;
        if (mi >= 0 && mi <= 63 && mj >= 0 && mj <= 63)
            d2 = sqd[192 + lane] + sqd[(oi + 3) * 64 + mj] - 2.0 * dotsd[lane * 50 + oo];
        dotsd[lane * 50 + oo] = d2;
    }
    __syncthreads();
    // phase 3: top-9 largest d^2 (only the SET matters downstream; ties -> lower index)
    if (wv == 0) {
        unsigned long long mask = 0ull;
        for (int k = 0; k < 9; ++k) {
            double best = -1e308; int bi = 0;
            for (int oo = 0; oo < 49; ++oo) {
                if ((mask >> oo) & 1ull) continue;
                double vv = dotsd[lane * 50 + oo];
                if (vv > best) { best = vv; bi = oo; }
            }
            mask |= (1ull << bi);
            sels[lane * 9 + k] = bi;
        }
    }
    __syncthreads();
    int rk[9], cj[9];
    #pragma unroll
    for (int k = 0; k < 9; ++k) {
        int oo = sels[lane * 9 + k];
        rk[k] = oo / 7;
        cj[k] = lane + (oo % 7) - 3;
    }
    // phase 4: f32 gather mean over selected neighbors, 8 stages of 8 channels
    for (int q = 0; q < 8; ++q) {
        __syncthreads();
        for (int s = t; s < 896; s += 256) {            // 7r x 8ch x 16 float4 chunks
            int rc = s >> 4, x4 = s & 15;
            int r = rc >> 3, c = rc & 7;
            int gr = i - 3 + r;
            if (gr >= 0 && gr <= 63)
                *(float4*)(tileq + rc * 68 + x4 * 4) =
                    *(const float4*)(catp(o, b * 128 + q * 8 + c) + gr * 64 + x4 * 4);
        }
        __syncthreads();
        #pragma unroll
        for (int cc = 0; cc < 2; ++cc) {
            int c = wv * 2 + cc;
            float s = 0.f;
            #pragma unroll
            for (int k = 0; k < 9; ++k) s += tileq[(rk[k] * 8 + c) * 68 + cj[k]];
            float outv = s * (1.f / 9.f) - tileq[(24 + c) * 68 + lane];
            catp(o, b * 128 + 64 + q * 8 + c)[i * 64 + lane] = outv;
        }
    }
}

// ---------------- K3: 3x3 conv (128->64) + BN + ReLU -> feat planes
__global__ __launch_bounds__(256) void k3_conv(
    float* __restrict__ o, const float* __restrict__ w1,
    const float* __restrict__ b1, const float* __restrict__ g, const float* __restrict__ be,
    const float* __restrict__ m, const float* __restrict__ v)
{
    __shared__ __align__(16) float tile[3 * 32 * 72];
    int blk = blockIdx.x;
    int b = blk >> 6, i = blk & 63;
    int t = threadIdx.x;
    int co = t & 63, jg = t >> 6;
    float acc[16];
    #pragma unroll
    for (int jj = 0; jj < 16; ++jj) acc[jj] = 0.f;
    const float4 z4 = make_float4(0.f, 0.f, 0.f, 0.f);
    for (int st = 0; st < 4; ++st) {
        __syncthreads();
        for (int s = t; s < 96; s += 256) {
            float* d = tile + s * 72;
            *(float4*)(d) = z4;
            *(float4*)(d + 68) = z4;
        }
        for (int f = t; f < 1536; f += 256) {
            int x4 = f & 15, ci = (f >> 4) & 31, ry = f >> 9;
            int gr = i - 1 + ry;
            float4 val = z4;
            if (gr >= 0 && gr <= 63)
                val = *(const float4*)(catp(o, b * 128 + st * 32 + ci) + gr * 64 + x4 * 4);
            *(float4*)(tile + (ry * 32 + ci) * 72 + 4 + x4 * 4) = val;
        }
        __syncthreads();
        for (int cl = 0; cl < 32; ++cl) {
            int ci = st * 32 + cl;
            const float* wrow = w1 + (co * 128 + ci) * 9;
            #pragma unroll
            for (int ry = 0; ry < 3; ++ry) {
                float w0 = wrow[ry * 3 + 0];
                float w1f = wrow[ry * 3 + 1];
                float w2 = wrow[ry * 3 + 2];
                const float* xr = tile + (ry * 32 + cl) * 72 + jg * 16;
                float4 q0 = *(const float4*)(xr);
                float4 q1 = *(const float4*)(xr + 4);
                float4 q2 = *(const float4*)(xr + 8);
                float4 q3 = *(const float4*)(xr + 12);
                float4 q4 = *(const float4*)(xr + 16);
                float4 q5 = *(const float4*)(xr + 20);
                float xv[24] = { q0.x,q0.y,q0.z,q0.w, q1.x,q1.y,q1.z,q1.w,
                                 q2.x,q2.y,q2.z,q2.w, q3.x,q3.y,q3.z,q3.w,
                                 q4.x,q4.y,q4.z,q4.w, q5.x,q5.y,q5.z,q5.w };
                #pragma unroll
                for (int jj = 0; jj < 16; ++jj)
                    acc[jj] = fmaf(w0, xv[jj + 3], fmaf(w1f, xv[jj + 4], fmaf(w2, xv[jj + 5], acc[jj])));
            }
        }
    }
    float sc = g[co] * rsqrtf(v[co] + 1e-5f);
    float sh = b1[co] - m[co];
    float bb = be[co];
    float* fp = o + (size_t)(b * 64 + co) * 65536 + i * 64 + jg * 16;
    #pragma unroll
    for (int q = 0; q < 4; ++q) {
        float4 ov;
        ov.x = fmaxf(0.f, fmaf(acc[q * 4 + 0] + sh, sc, bb));
        ov.y = fmaxf(0.f, fmaf(acc[q * 4 + 1] + sh, sc, bb));
        ov.z = fmaxf(0.f, fmaf(acc[q * 4 + 2] + sh, sc, bb));
        ov.w = fmaxf(0.f, fmaf(acc[q * 4 + 3] + sh, sc, bb));
        *(float4*)(fp + q * 4) = ov;
    }
}

// ---------------- K4a: per-plane spatial mean -> slot[12288]
__global__ __launch_bounds__(256) void k4_mean(float* __restrict__ o) {
    int q = blockIdx.x, t = threadIdx.x;
    const float* p = o + (size_t)q * 65536;
    float s = 0.f;
    for (int k = t; k < 4096; k += 256) s += p[k];
    #pragma unroll
    for (int off = 32; off > 0; off >>= 1) s += __shfl_down(s, off, 64);
    __shared__ float red[4];
    if ((t & 63) == 0) red[t >> 6] = s;
    __syncthreads();
    if (t == 0) o[(size_t)q * 65536 + 12288] = (red[0] + red[1] + red[2] + red[3]) * (1.f / 4096.f);
}

// ---------------- K4b: 1x1 conv + BN + sigmoid -> slot[12289]
__global__ __launch_bounds__(256) void k4_att(float* __restrict__ o, const float* __restrict__ wa,
    const float* __restrict__ g, const float* __restrict__ be, const float* __restrict__ m, const float* __restrict__ v) {
    int t = threadIdx.x;
    int b = t >> 6, co = t & 63;
    const float* wr = wa + co * 64;
    float s = 0.f;
    for (int ci = 0; ci < 64; ++ci) s = fmaf(wr[ci], o[(size_t)(b * 64 + ci) * 65536 + 12288], s);
    float sc = g[co] * rsqrtf(v[co] + 1e-5f);
    float y = fmaf(s - m[co], sc, be[co]);
    o[(size_t)t * 65536 + 12289] = 1.f / (1.f + expf(-y));
}

// ---------------- K5: out = bilinear_x4(feat)*att, f32 in place over own slot (race-free).
__global__ __launch_bounds__(256) void k5_up(float* __restrict__ o) {
    __shared__ __align__(16) float fplane[4096];
    int bc = blockIdx.x;
    int t = threadIdx.x;
    float* slot = o + (size_t)bc * 65536;
    #pragma unroll
    for (int kk = 0; kk < 4; ++kk) {
        int idx = t + 256 * kk;
        *(float4*)(fplane + idx * 4) = *(const float4*)(slot + idx * 4);
    }
    float att = slot[12289];
    __syncthreads();
    int ox = t;
    float fx = ox * 0.25f - 0.375f;
    int ix = (int)floorf(fx);
    float wx = fx - (float)ix;
    int x0 = ix < 0 ? 0 : ix;
    int x1 = (ix + 1 > 63) ? 63 : ix + 1;
    for (int oy = 0; oy < 256; ++oy) {
        float fy = oy * 0.25f - 0.375f;
        int iy = (int)floorf(fy);
        float wy = fy - (float)iy;
        int y0 = iy < 0 ? 0 : iy;
        int y1 = (iy + 1 > 63) ? 63 : iy + 1;
        float a  = fplane[y0 * 64 + x0], b_ = fplane[y0 * 64 + x1];
        float c_ = fplane[y1 * 64 + x0], d_ = fplane[y1 * 64 + x1];
        float top = a + wx * (b_ - a);
        float bot = c_ + wx * (d_ - c_);
        float val = (top + wy * (bot - top)) * att;
        slot[oy * 256 + ox] = val;
    }
}

extern "C" void kernel_launch(void* const* d_in, const int* in_sizes, int n_in,
                              void* d_out, int out_size, void* d_ws, size_t ws_size,
                              hipStream_t stream) {
    const float* x     = (const float*)d_in[0];
    const float* wd    = (const float*)d_in[1];
    const float* bd    = (const float*)d_in[2];
    const float* bnd_g = (const float*)d_in[3];
    const float* bnd_b = (const float*)d_in[4];
    const float* bnd_m = (const float*)d_in[5];
    const float* bnd_v = (const float*)d_in[6];
    const float* w1    = (const float*)d_in[7];
    const float* b1    = (const float*)d_in[8];
    const float* bn1_g = (const float*)d_in[9];
    const float* bn1_b = (const float*)d_in[10];
    const float* bn1_m = (const float*)d_in[11];
    const float* bn1_v = (const float*)d_in[12];
    const float* wa    = (const float*)d_in[13];
    const float* bna_g = (const float*)d_in[14];
    const float* bna_b = (const float*)d_in[15];
    const float* bna_m = (const float*)d_in[16];
    const float* bna_v = (const float*)d_in[17];

    float* o = (float*)d_out;   // f32 output; all scratch lives inside d_out; d_ws unused

    hipLaunchKernelGGL(k1_convds, dim3(1024), dim3(256), 0, stream,
                       x, wd, bd, bnd_g, bnd_b, bnd_m, bnd_v, o);
    hipLaunchKernelGGL(k2_feat, dim3(256), dim3(256), 0, stream, o);
    hipLaunchKernelGGL(k3_conv, dim3(256), dim3(256), 0, stream,
                       o, w1, b1, bn1_g, bn1_b, bn1_m, bn1_v);
    hipLaunchKernelGGL(k4_mean, dim3(256), dim3(256), 0, stream, o);
    hipLaunchKernelGGL(k4_att, dim3(1), dim3(256), 0, stream,
                       o, wa, bna_g, bna_b, bna_m, bna_v);
    hipLaunchKernelGGL(k5_up, dim3(256), dim3(256), 0, stream, o);
}